// Round 2
// baseline (1527.098 us; speedup 1.0000x reference)
//
#include <hip/hip_runtime.h>
#include <math.h>

#define BB 512
#define TT 1024
#define LL 48
#define PF 8           // emission prefetch depth (loads in flight, per batch)

__device__ __forceinline__ float readlane_f(float v, int lane) {
    return __int_as_float(__builtin_amdgcn_readlane(__float_as_int(v), lane));
}

// Tournament argmax over s[0..47], first-max tie-break (epilogue only).
__device__ __forceinline__ void argmax48(const float* s, float& bestv, int& besti) {
    float val[24];
    int   idx[24];
#pragma unroll
    for (int k = 0; k < 24; ++k) {
        bool c = s[2 * k + 1] > s[2 * k];
        val[k] = c ? s[2 * k + 1] : s[2 * k];
        idx[k] = c ? 2 * k + 1 : 2 * k;
    }
#pragma unroll
    for (int k = 0; k < 12; ++k) {
        bool c = val[2 * k + 1] > val[2 * k];
        val[k] = c ? val[2 * k + 1] : val[2 * k];
        idx[k] = c ? idx[2 * k + 1] : idx[2 * k];
    }
#pragma unroll
    for (int k = 0; k < 6; ++k) {
        bool c = val[2 * k + 1] > val[2 * k];
        val[k] = c ? val[2 * k + 1] : val[2 * k];
        idx[k] = c ? idx[2 * k + 1] : idx[2 * k];
    }
#pragma unroll
    for (int k = 0; k < 3; ++k) {
        bool c = val[2 * k + 1] > val[2 * k];
        val[k] = c ? val[2 * k + 1] : val[2 * k];
        idx[k] = c ? idx[2 * k + 1] : idx[2 * k];
    }
    bool c01 = val[1] > val[0];
    float bv = c01 ? val[1] : val[0];
    int   bi = c01 ? idx[1] : idx[0];
    bool c2 = val[2] > bv;
    bestv = c2 ? val[2] : bv;
    besti = c2 ? idx[2] : bi;
}

// One Viterbi step for two independent chains, statement-interleaved for ILP.
// MUST be force-inlined: if this outlines, the by-ref state lands in scratch
// (round-1 failure mode: VGPR 104, VALUBusy 13.5%, 3x slowdown).
__device__ __attribute__((always_inline)) void step2(
    float& vA, float& vB, const float* __restrict__ tc,
    float eA, float eB,
    unsigned char* __restrict__ bpA, unsigned char* __restrict__ bpB,
    int t, int jc)
{
    float sA[LL], sB[LL];
#pragma unroll
    for (int i = 0; i < LL; ++i) {
        sA[i] = readlane_f(vA, i) + tc[i];
        sB[i] = readlane_f(vB, i) + tc[i];
    }

    // value-only max3 trees (depth 4), interleaved
    float m1A[16], m1B[16];
#pragma unroll
    for (int k = 0; k < 16; ++k) {
        m1A[k] = fmaxf(fmaxf(sA[3 * k], sA[3 * k + 1]), sA[3 * k + 2]);
        m1B[k] = fmaxf(fmaxf(sB[3 * k], sB[3 * k + 1]), sB[3 * k + 2]);
    }
    float m2A[6], m2B[6];
#pragma unroll
    for (int k = 0; k < 5; ++k) {
        m2A[k] = fmaxf(fmaxf(m1A[3 * k], m1A[3 * k + 1]), m1A[3 * k + 2]);
        m2B[k] = fmaxf(fmaxf(m1B[3 * k], m1B[3 * k + 1]), m1B[3 * k + 2]);
    }
    m2A[5] = m1A[15];
    m2B[5] = m1B[15];
    float bestA = fmaxf(fmaxf(fmaxf(m2A[0], m2A[1]), m2A[2]),
                        fmaxf(fmaxf(m2A[3], m2A[4]), m2A[5]));
    float bestB = fmaxf(fmaxf(fmaxf(m2B[0], m2B[1]), m2B[2]),
                        fmaxf(fmaxf(m2B[3], m2B[4]), m2B[5]));

    vA = bestA + eA;                          // serial chains continue here
    vB = bestB + eB;

    // off-chain: first i with s[i]==best (exact: best is bitwise one of s)
    int a0 = 63, a1 = 63, a2 = 63, a3 = 63;
    int b0 = 63, b1 = 63, b2 = 63, b3 = 63;
#pragma unroll
    for (int k = 11; k >= 0; --k) {           // descending => lowest k wins
        if (sA[k]      == bestA) a0 = k;
        if (sA[12 + k] == bestA) a1 = 12 + k;
        if (sA[24 + k] == bestA) a2 = 24 + k;
        if (sA[36 + k] == bestA) a3 = 36 + k;
        if (sB[k]      == bestB) b0 = k;
        if (sB[12 + k] == bestB) b1 = 12 + k;
        if (sB[24 + k] == bestB) b2 = 24 + k;
        if (sB[36 + k] == bestB) b3 = 36 + k;
    }
    int argA = min(min(a0, a1), min(a2, a3)); // first-max tie-break
    int argB = min(min(b0, b1), min(b2, b3));

    bpA[(t - 1) * LL + jc] = (unsigned char)argA;
    bpB[(t - 1) * LL + jc] = (unsigned char)argB;
}

// One wave handles TWO batch elements (independent Viterbi chains) so the
// ~60% dependency-stall bubbles of one chain are filled by the other.
// waves_per_eu(1,1): grant the full VGPR file; LDS (98KB) caps at 1 WG/CU anyway.
__global__ __launch_bounds__(64)
__attribute__((amdgpu_waves_per_eu(1, 1)))
void viterbi_kernel(
    const float* __restrict__ emissions,   // [B,T,L]
    const float* __restrict__ transitions, // [L,L]
    const float* __restrict__ start_tr,    // [L]
    const float* __restrict__ end_tr,      // [L]
    int* __restrict__ out)                 // [B,T] int32
{
    extern __shared__ unsigned char bp[];  // 2 * (TT-1)*LL = 98,208 B
    unsigned char* bpA = bp;
    unsigned char* bpB = bp + (TT - 1) * LL;

    const int bA = blockIdx.x * 2;
    const int bB = bA + 1;
    const int j  = threadIdx.x;
    const int jc = (j < LL) ? j : (LL - 1);       // lanes 48-63 mirror lane 47

    // Transition column jc in registers: tc[i] = transitions[i][jc] (shared A/B)
    float tc[LL];
#pragma unroll
    for (int i = 0; i < LL; ++i)
        tc[i] = transitions[i * LL + jc];

    const float* emA = emissions + (size_t)bA * TT * LL;
    const float* emB = emissions + (size_t)bB * TT * LL;

    float vA = start_tr[jc] + emA[jc];
    float vB = start_tr[jc] + emB[jc];

    // 8-deep emission prefetch rings, one per batch.
    float erA[PF], erB[PF];
#pragma unroll
    for (int k = 0; k < PF; ++k) {
        erA[k] = emA[(size_t)(1 + k) * LL + jc];
        erB[k] = emB[(size_t)(1 + k) * LL + jc];
    }

    // Main loop: blocks of 8 with compile-time-constant ring indices.
    int tb = 1;
    for (; tb + PF <= TT; tb += PF) {
#pragma unroll
        for (int k = 0; k < PF; ++k) {
            int t = tb + k;
            float eA = erA[k];
            float eB = erB[k];
            int tn = t + PF; if (tn > TT - 1) tn = TT - 1;   // scalar clamp
            erA[k] = emA[(size_t)tn * LL + jc];   // refills: loads in flight
            erB[k] = emB[(size_t)tn * LL + jc];
            step2(vA, vB, tc, eA, eB, bpA, bpB, t, jc);
        }
    }
    // Tail: remaining steps, emissions already resident in the rings.
#pragma unroll
    for (int k = 0; k < PF - 1; ++k) {
        int t = tb + k;
        if (t < TT) step2(vA, vB, tc, erA[k], erB[k], bpA, bpB, t, jc);
    }

    // ---- epilogue: final tags (tournament keeps exact tie-break) ----
    vA += end_tr[jc];
    vB += end_tr[jc];
    float sfA[LL], sfB[LL];
#pragma unroll
    for (int i = 0; i < LL; ++i) {
        sfA[i] = readlane_f(vA, i);
        sfB[i] = readlane_f(vB, i);
    }
    float bvA, bvB; int tagA, tagB;
    argmax48(sfA, bvA, tagA);                     // wave-uniform
    argmax48(sfB, bvB, tagB);

    int* obA = out + (size_t)bA * TT;
    int* obB = out + (size_t)bB * TT;
    if (j == 0) {
        obA[TT - 1] = tagA;
        obB[TT - 1] = tagB;
    }

    // ---- backtrack: coalesced row loads + readlane chains, both batches ----
    for (int hi = TT - 2; hi >= 0; hi -= 32) {
        int lo = hi - 31; if (lo < 0) lo = 0;
        int n = hi - lo + 1;

        unsigned int rowA[32], rowB[32];
#pragma unroll
        for (int k = 0; k < 32; ++k) {
            rowA[k] = (unsigned int)bpA[(lo + k) * LL + jc];
            rowB[k] = (unsigned int)bpB[(lo + k) * LL + jc];
        }

        int outA = 0, outB = 0;
#pragma unroll
        for (int k = 31; k >= 0; --k) {
            if (k < n) {
                tagA = __builtin_amdgcn_readlane((int)rowA[k], tagA);
                outA = (j == k) ? tagA : outA;    // tag is SGPR -> one cndmask
                tagB = __builtin_amdgcn_readlane((int)rowB[k], tagB);
                outB = (j == k) ? tagB : outB;
            }
        }
        if (j < n) {
            obA[lo + j] = outA;
            obB[lo + j] = outB;
        }
    }
}

extern "C" void kernel_launch(void* const* d_in, const int* in_sizes, int n_in,
                              void* d_out, int out_size, void* d_ws, size_t ws_size,
                              hipStream_t stream) {
    const float* emissions   = (const float*)d_in[0];
    // d_in[1] = mask — unused by the reference decode body
    const float* transitions = (const float*)d_in[2];
    const float* start_tr    = (const float*)d_in[3];
    const float* end_tr      = (const float*)d_in[4];
    int* out = (int*)d_out;

    const int lds_bytes = 2 * (TT - 1) * LL;      // 98,208 B (< 160 KiB/CU)

    static bool attr_set = false;
    if (!attr_set) {
        // Opt-in for >64 KiB dynamic LDS (no-op / harmless if unsupported).
        (void)hipFuncSetAttribute((const void*)viterbi_kernel,
                                  hipFuncAttributeMaxDynamicSharedMemorySize,
                                  lds_bytes);
        attr_set = true;
    }

    viterbi_kernel<<<dim3(BB / 2), dim3(64), lds_bytes, stream>>>(
        emissions, transitions, start_tr, end_tr, out);
}

// Round 3
// 924.192 us; speedup vs baseline: 1.6524x; 1.6524x over previous
//
#include <hip/hip_runtime.h>
#include <math.h>

#define BB 512
#define TT 1024
#define LL 48
#define PF 8           // emission prefetch depth (loads in flight, per wave)
#define HALF 24        // previous-states per wave

__device__ __forceinline__ float readlane_f(float v, int lane) {
    return __int_as_float(__builtin_amdgcn_readlane(__float_as_int(v), lane));
}

// Tournament argmax over s[0..47], first-max tie-break (epilogue only).
__device__ __forceinline__ void argmax48(const float* s, float& bestv, int& besti) {
    float val[24];
    int   idx[24];
#pragma unroll
    for (int k = 0; k < 24; ++k) {
        bool c = s[2 * k + 1] > s[2 * k];
        val[k] = c ? s[2 * k + 1] : s[2 * k];
        idx[k] = c ? 2 * k + 1 : 2 * k;
    }
#pragma unroll
    for (int k = 0; k < 12; ++k) {
        bool c = val[2 * k + 1] > val[2 * k];
        val[k] = c ? val[2 * k + 1] : val[2 * k];
        idx[k] = c ? idx[2 * k + 1] : idx[2 * k];
    }
#pragma unroll
    for (int k = 0; k < 6; ++k) {
        bool c = val[2 * k + 1] > val[2 * k];
        val[k] = c ? val[2 * k + 1] : val[2 * k];
        idx[k] = c ? idx[2 * k + 1] : idx[2 * k];
    }
#pragma unroll
    for (int k = 0; k < 3; ++k) {
        bool c = val[2 * k + 1] > val[2 * k];
        val[k] = c ? val[2 * k + 1] : val[2 * k];
        idx[k] = c ? idx[2 * k + 1] : idx[2 * k];
    }
    bool c01 = val[1] > val[0];
    float bv = c01 ? val[1] : val[0];
    int   bi = c01 ? idx[1] : idx[0];
    bool c2 = val[2] > bv;
    bestv = c2 ? val[2] : bv;
    besti = c2 ? idx[2] : bi;
}

// Two waves cooperate on ONE chain: wave w reduces previous-states
// i in [24w, 24w+24). Per-wave issue work halves vs the 1-wave kernel and
// the grid doubles to 1024 waves = all 1024 SIMDs. One LDS exchange +
// raw s_barrier per step (NOT __syncthreads: that drains vmcnt(0) and
// would kill the emission prefetch ring).
__global__ __launch_bounds__(128) void viterbi_kernel(
    const float* __restrict__ emissions,   // [B,T,L]
    const float* __restrict__ transitions, // [L,L]
    const float* __restrict__ start_tr,    // [L]
    const float* __restrict__ end_tr,      // [L]
    int* __restrict__ out)                 // [B,T] int32
{
    __shared__ unsigned char bp[(TT - 1) * LL];   // 49,104 B backpointers
    __shared__ uint2 xch[2][2][64];               // [parity][half][lane] = (m bits, arg)

    const int b   = blockIdx.x;
    const int tid = threadIdx.x;
    const int w   = tid >> 6;                     // wave id: 0 = low half i<24
    const int j   = tid & 63;
    const int jc  = (j < LL) ? j : (LL - 1);      // lanes 48-63 mirror lane 47
    const int ibase = w * HALF;

    // Own half of transition column jc: tc[i] = transitions[ibase+i][jc]
    float tc[HALF];
#pragma unroll
    for (int i = 0; i < HALF; ++i)
        tc[i] = transitions[(ibase + i) * LL + jc];

    const float* em = emissions + (size_t)b * TT * LL;

    // v replicated in BOTH waves (identical arithmetic each step keeps it bitwise equal)
    float v = start_tr[jc] + em[jc];

    // 8-deep emission prefetch ring (both waves load same lines; L1 absorbs).
    float er[PF];
#pragma unroll
    for (int k = 0; k < PF; ++k)
        er[k] = em[(size_t)(1 + k) * LL + jc];

    // One Viterbi step. parity must be a compile-time constant (tb is always odd).
    //
    // Race-freedom of the single-barrier + parity-double-buffer handshake:
    // per wave: W(t,p) lgkmcnt(0) B(t) R(t,p) | W(t+1,p^1) ... . Wave X's
    // W(t+1) writes buffer p^1, last read at R(t-1). Y's R(t-1) data is
    // complete before Y's lgkmcnt(0)+B(t), and X's W(t+1) is after B(t). QED.
    auto step = [&](int t, float e, int parity) {
        // own-half scores
        float s[HALF];
#pragma unroll
        for (int i = 0; i < HALF; ++i)
            s[i] = readlane_f(v, ibase + i) + tc[i];

        // value-only max tree over 24 (depth 3)
        float m1[8];
#pragma unroll
        for (int k = 0; k < 8; ++k)
            m1[k] = fmaxf(fmaxf(s[3 * k], s[3 * k + 1]), s[3 * k + 2]);
        float mA = fmaxf(fmaxf(m1[0], m1[1]), m1[2]);
        float mB = fmaxf(fmaxf(m1[3], m1[4]), m1[5]);
        float mC = fmaxf(m1[6], m1[7]);
        float best_own = fmaxf(fmaxf(mA, mB), mC);

        // off-chain: first i in own half with s[i]==best_own (exact bitwise member)
        int i0 = 63, i1 = 63;
#pragma unroll
        for (int k = 11; k >= 0; --k) {           // descending => lowest k wins
            if (s[k]      == best_own) i0 = ibase + k;
            if (s[12 + k] == best_own) i1 = ibase + 12 + k;
        }
        int arg_own = min(i0, i1);

        // exchange halves: write own (m,arg), barrier, read other
        xch[parity][w][j] = make_uint2(__float_as_uint(best_own), (unsigned)arg_own);
        asm volatile("s_waitcnt lgkmcnt(0)" ::: "memory");  // LDS-only drain
        __builtin_amdgcn_s_barrier();                       // raw: vmcnt untouched
        uint2 o = xch[parity][w ^ 1][jc];
        float m_oth = __uint_as_float(o.x);
        int   a_oth = (int)o.y;

        // combine; ties go to the LOW half (reference = first-max over i)
        float m_low  = (w == 0) ? best_own : m_oth;
        int   a_low  = (w == 0) ? arg_own  : a_oth;
        float m_high = (w == 0) ? m_oth    : best_own;
        int   a_high = (w == 0) ? a_oth    : arg_own;
        bool  hw_    = m_high > m_low;            // strict: low half wins ties
        float bestv  = hw_ ? m_high : m_low;
        int   barg   = hw_ ? a_high : a_low;

        v = bestv + e;                            // serial chain continues here

        if (w == 0)                               // wave0 owns the bp trail
            bp[(t - 1) * LL + jc] = (unsigned char)barg;
    };

    // Main loop: blocks of 8 with compile-time-constant ring indices.
    // tb starts at 1 and steps by 8 => tb always odd => parity(t) = (k+1)&1.
    int tb = 1;
    for (; tb + PF <= TT; tb += PF) {
#pragma unroll
        for (int k = 0; k < PF; ++k) {
            int t = tb + k;
            float e = er[k];
            int tn = t + PF; if (tn > TT - 1) tn = TT - 1;   // scalar clamp
            er[k] = em[(size_t)tn * LL + jc];     // refill: 8 loads in flight
            step(t, e, (k + 1) & 1);
        }
    }
    // Tail: remaining steps, emissions already resident in er[].
#pragma unroll
    for (int k = 0; k < PF - 1; ++k) {
        int t = tb + k;
        if (t < TT) step(t, er[k], (k + 1) & 1);
    }

    // ---- epilogue + backtrack: wave0 only (no barriers below) ----
    if (w == 0) {
        float vf = v + end_tr[jc];
        float sf[LL];
#pragma unroll
        for (int i = 0; i < LL; ++i)
            sf[i] = readlane_f(vf, i);
        float bestv; int tag;
        argmax48(sf, bestv, tag);                 // tag is wave-uniform

        int* ob = out + (size_t)b * TT;
        if (j == 0) ob[TT - 1] = tag;

        // backtrack: 32 coalesced row loads + readlane chain + 1 store/chunk
        for (int hi = TT - 2; hi >= 0; hi -= 32) {
            int lo = hi - 31; if (lo < 0) lo = 0;
            int n = hi - lo + 1;

            unsigned int row[32];
#pragma unroll
            for (int k = 0; k < 32; ++k)
                row[k] = (unsigned int)bp[(lo + k) * LL + jc];

            int outv = 0;
#pragma unroll
            for (int k = 31; k >= 0; --k) {
                if (k < n) {
                    tag = __builtin_amdgcn_readlane((int)row[k], tag);
                    outv = (j == k) ? tag : outv; // tag is SGPR -> one cndmask
                }
            }
            if (j < n) ob[lo + j] = outv;
        }
    }
}

extern "C" void kernel_launch(void* const* d_in, const int* in_sizes, int n_in,
                              void* d_out, int out_size, void* d_ws, size_t ws_size,
                              hipStream_t stream) {
    const float* emissions   = (const float*)d_in[0];
    // d_in[1] = mask — unused by the reference decode body
    const float* transitions = (const float*)d_in[2];
    const float* start_tr    = (const float*)d_in[3];
    const float* end_tr      = (const float*)d_in[4];
    int* out = (int*)d_out;

    viterbi_kernel<<<dim3(BB), dim3(128), 0, stream>>>(
        emissions, transitions, start_tr, end_tr, out);
}

// Round 4
// 528.854 us; speedup vs baseline: 2.8876x; 1.7475x over previous
//
#include <hip/hip_runtime.h>
#include <math.h>

#define BB 512
#define TT 1024
#define LL 48
#define PF 8            // emission prefetch depth (loads in flight)
#define TSTRIDE 49      // padded T row stride: bank = (17*i + j) % 32, conflict-free

__device__ __forceinline__ float readlane_f(float v, int lane) {
    return __int_as_float(__builtin_amdgcn_readlane(__float_as_int(v), lane));
}

// One DPP butterfly/broadcast stage of a full-wave max (register-file cross-lane,
// ~VALU latency; NOT ds_bpermute and NOT an LDS round-trip).
template <int CTRL>
__device__ __forceinline__ float dppmax(float x) {
    int y = __builtin_amdgcn_update_dpp(__float_as_int(x), __float_as_int(x),
                                        CTRL, 0xF, 0xF, false);
    return fmaxf(x, __int_as_float(y));
}

// Wave max of z, then lowest-lane index of bitwise equality (== reference
// first-max argmax; lanes holding -INF never match). ~13 VALU + 1 SALU.
__device__ __forceinline__ int wave_argmax(float z) {
    float r = z;
    r = dppmax<0xB1>(r);    // quad_perm [1,0,3,2] : xor 1
    r = dppmax<0x4E>(r);    // quad_perm [2,3,0,1] : xor 2
    r = dppmax<0x141>(r);   // row_half_mirror     : xor 4
    r = dppmax<0x140>(r);   // row_mirror          : xor 8
    r = dppmax<0x142>(r);   // row_bcast15         : 16->31, 47->63 merge
    r = dppmax<0x143>(r);   // row_bcast31         : lane 63 = full-wave max
    float m = readlane_f(r, 63);
    unsigned long long eq = __ballot(z == m);
    return (int)__builtin_ctzll(eq);     // s_ff1: lowest index wins ties
}

// Forward pass stores VALUES ONLY (no per-step argmax scan): the 48 cmp +
// 48 cndmask + min-tree (~108 instr/step, round-0) are gone, and with them
// the anti-dependency that serialized step t's scan against step t+1's
// readlanes. Backtrack recomputes the single needed argmax per step from
// the stored Viterbi rows — bitwise-identical floats, ffs tie-break.
__global__ __launch_bounds__(64) void viterbi_kernel(
    const float* __restrict__ emissions,   // [B,T,L]
    const float* __restrict__ transitions, // [L,L]
    const float* __restrict__ start_tr,    // [L]
    const float* __restrict__ end_tr,      // [L]
    int* __restrict__ out,                 // [B,T] int32
    float* __restrict__ vws)               // workspace: [B][T][L] viterbi rows
{
    __shared__ float tlds[LL * TSTRIDE];   // T padded for backtrack column reads

    const int b  = blockIdx.x;
    const int j  = threadIdx.x;
    const int jc = (j < LL) ? j : (LL - 1);       // lanes 48-63 mirror lane 47

    // Transition column jc in registers (forward); T into LDS (backtrack).
    float tc[LL];
#pragma unroll
    for (int i = 0; i < LL; ++i) {
        tc[i] = transitions[i * LL + jc];
        tlds[i * TSTRIDE + jc] = tc[i];    // lanes 48-63 dup-write col 47: same value
    }

    const float* em = emissions + (size_t)b * TT * LL;
    float* vr_g = vws + (size_t)b * TT * LL;      // this chain's [T][48] rows

    float v = start_tr[jc] + em[jc];
    vr_g[jc] = v;                                  // row 0 (dup lanes write same value)

    // 8-deep emission prefetch ring.
    float er[PF];
#pragma unroll
    for (int k = 0; k < PF; ++k)
        er[k] = em[(size_t)(1 + k) * LL + jc];

    // One value-only Viterbi step (serial chain: v -> v).
    auto step = [&](int t, float e) {
        float s[LL];
#pragma unroll
        for (int i = 0; i < LL; ++i)
            s[i] = readlane_f(v, i) + tc[i];

        float m1[16];
#pragma unroll
        for (int k = 0; k < 16; ++k)
            m1[k] = fmaxf(fmaxf(s[3 * k], s[3 * k + 1]), s[3 * k + 2]);
        float m2[6];
#pragma unroll
        for (int k = 0; k < 5; ++k)
            m2[k] = fmaxf(fmaxf(m1[3 * k], m1[3 * k + 1]), m1[3 * k + 2]);
        m2[5] = m1[15];
        float best = fmaxf(fmaxf(fmaxf(m2[0], m2[1]), m2[2]),
                           fmaxf(fmaxf(m2[3], m2[4]), m2[5]));

        v = best + e;                              // chain continues here
        vr_g[(size_t)t * LL + jc] = v;             // off-chain coalesced 192B store
    };

    // Main loop: blocks of 8 with compile-time-constant ring indices.
    int tb = 1;
    for (; tb + PF <= TT; tb += PF) {
#pragma unroll
        for (int k = 0; k < PF; ++k) {
            int t = tb + k;
            float e = er[k];
            int tn = t + PF; if (tn > TT - 1) tn = TT - 1;   // scalar clamp
            er[k] = em[(size_t)tn * LL + jc];      // refill: 8 loads in flight
            step(t, e);
        }
    }
#pragma unroll
    for (int k = 0; k < PF - 1; ++k) {
        int t = tb + k;
        if (t < TT) step(t, er[k]);
    }

    // ---- final tag: wave-parallel argmax of v + end ----
    float vf = (j < LL) ? (v + end_tr[jc]) : -INFINITY;
    int tag = wave_argmax(vf);                     // uniform (SGPR) tag

    int* ob = out + (size_t)b * TT;
    if (j == 0) ob[TT - 1] = tag;

    // ---- backtrack: recompute argmax only along the path ----
    // tag_p = argmax_i( v_p[i] + T[i][tag_{p+1}] ), p = T-2 .. 0.
    // v-rows prefetched 32 at a time (addresses tag-independent).
    for (int hi = TT - 2; hi >= 0; hi -= 32) {
        int lo = hi - 31; if (lo < 0) lo = 0;
        int n = hi - lo + 1;                       // wave-uniform

        float vr[32];
#pragma unroll
        for (int k = 31; k >= 0; --k)              // issue order == consume order
            if (k < n) vr[k] = vr_g[(size_t)(lo + k) * LL + jc];

        int outv = 0;
#pragma unroll
        for (int k = 31; k >= 0; --k) {
            if (k < n) {
                // lane i reads T[i][tag]: dwords (17*i + tag) % 32 -> no conflicts
                float tcol = tlds[jc * TSTRIDE + tag];
                float z = (j < LL) ? (vr[k] + tcol) : -INFINITY;
                tag = wave_argmax(z);              // chain: ds_read+add+dpp+ballot
                outv = (j == k) ? tag : outv;      // tag is SGPR -> one cndmask
            }
        }
        if (j < n) ob[lo + j] = outv;
    }
}

extern "C" void kernel_launch(void* const* d_in, const int* in_sizes, int n_in,
                              void* d_out, int out_size, void* d_ws, size_t ws_size,
                              hipStream_t stream) {
    const float* emissions   = (const float*)d_in[0];
    // d_in[1] = mask — unused by the reference decode body
    const float* transitions = (const float*)d_in[2];
    const float* start_tr    = (const float*)d_in[3];
    const float* end_tr      = (const float*)d_in[4];
    int* out = (int*)d_out;

    // Viterbi rows: B * T * L * 4 = 100,663,296 B in the provided workspace.
    float* vws = (float*)d_ws;

    viterbi_kernel<<<dim3(BB), dim3(64), 0, stream>>>(
        emissions, transitions, start_tr, end_tr, out, vws);
}